// Round 9
// baseline (684.884 us; speedup 1.0000x reference)
//
#include <hip/hip_runtime.h>

#define EPS 1e-3f

// Tensor geometry (fixed for this problem):
// y1 (L1 pre-act): interleaved (2, 4, 21,256,256, 4)  = (b, c/4, z,y,x, c%4)
// m1: (2,21,256,256)
// L2 out (h2): (2,32,11,128,128)  m2: (2,11,128,128)
// L3 out (h3): (2,64,5,64,64)     m3: (2,5,64,64)
// L4 out:      (2,64,2,64,64) -> d_out (2,128,64,64) same layout
//
// Lessons encoded:
//  - Weight pointers must be BLOCK-uniform (scalar s_load path). (r2: 3.6x regression)
//  - In-thread register prefetch >~20 regs spills to scratch, hides nothing. (r7)
//  - The working latency-hiding lever is MANY SMALL BLOCKS (128-thr, 2-wave
//    barrier groups, ~11 blocks/CU) interleaving staging/compute phases
//    across blocks -- proved by conv_l3 r5 (324 -> ~80 us). LDS-halving alone
//    at 4-wave granularity did NOT raise achieved occupancy. (r8)
//  - Scatter is memory-REQUEST bound -> channel-quad interleaved y1. (r5/r6)

// ---------------- Weight repack + BN fold ----------------
__global__ __launch_bounds__(256) void repack(
    const float* __restrict__ w2, const float* __restrict__ g2, const float* __restrict__ b2,
    const float* __restrict__ rm2, const float* __restrict__ rv2,
    const float* __restrict__ w3, const float* __restrict__ g3, const float* __restrict__ b3,
    const float* __restrict__ rm3, const float* __restrict__ rv3,
    const float* __restrict__ w4, const float* __restrict__ g4, const float* __restrict__ b4,
    const float* __restrict__ rm4, const float* __restrict__ rv4,
    float* __restrict__ wT2, float* __restrict__ wT3, float* __restrict__ wT4,
    float* __restrict__ shb)
{
    const int i = blockIdx.x * 256 + threadIdx.x;
    if (i < 13824) {                       // wT2[(cin*27+tap)*32+oc], 16x27x32
        const int cin = i / 864, tap = (i / 32) % 27, oc = i & 31;
        const float inv = g2[oc] * rsqrtf(rv2[oc] + EPS);
        wT2[i] = w2[(oc * 16 + cin) * 27 + tap] * inv;
    } else if (i < 69120) {                // wT3[(cin*27+tap)*64+oc], 32x27x64
        const int j = i - 13824;
        const int cin = j / 1728, tap = (j / 64) % 27, oc = j & 63;
        const float inv = g3[oc] * rsqrtf(rv3[oc] + EPS);
        wT3[j] = w3[(oc * 32 + cin) * 27 + tap] * inv;
    } else if (i < 81408) {                // wT4[(c*3+kz)*64+oc], 64x3x64
        const int j = i - 69120;
        const int c = j / 192, kz = (j / 64) % 3, oc = j & 63;
        const float inv = g4[oc] * rsqrtf(rv4[oc] + EPS);
        wT4[j] = w4[(oc * 64 + c) * 3 + kz] * inv;
    } else if (i < 81568) {                // shifts: sh2[32], sh3[64], sh4[64]
        const int j = i - 81408;
        if (j < 32) {
            const float inv = g2[j] * rsqrtf(rv2[j] + EPS);
            shb[j] = b2[j] - rm2[j] * inv;
        } else if (j < 96) {
            const int o = j - 32;
            const float inv = g3[o] * rsqrtf(rv3[o] + EPS);
            shb[j] = b3[o] - rm3[o] * inv;
        } else {
            const int o = j - 96;
            const float inv = g4[o] * rsqrtf(rv4[o] + EPS);
            shb[j] = b4[o] - rm4[o] * inv;
        }
    }
}

// ---------------- Layer 1: voxel scatter, one thread per (voxel, oc) ----------------
__global__ __launch_bounds__(256) void scatter_l1(
    const float* __restrict__ vf, const int* __restrict__ coors, int NV,
    const float* __restrict__ w1, float* __restrict__ y1, float* __restrict__ m1)
{
    __shared__ float ws[16 * 3 * 27];  // (oc, c, tap)
    for (int e = threadIdx.x; e < 16 * 3 * 27; e += 256) ws[e] = w1[e];
    __syncthreads();

    const int gid = blockIdx.x * 256 + threadIdx.x;
    const int i = gid >> 4;        // voxel
    const int oc = gid & 15;       // channel
    if (i >= NV) return;
    const int oc4 = oc >> 2, ocl = oc & 3;

    const int b = coors[4 * i + 0];
    const int z = coors[4 * i + 1];
    const int y = coors[4 * i + 2];
    const int x = coors[4 * i + 3];
    const float f0 = vf[3 * i + 0];
    const float f1 = vf[3 * i + 1];
    const float f2 = vf[3 * i + 2];

    int ozv[2], kzv[2], nz = 0;
    int oyv[2], kyv[2], ny = 0;
    int oxv[2], kxv[2], nx = 0;
#pragma unroll
    for (int k = 0; k < 3; ++k) {
        int t = z + 1 - k;
        if (t >= 0 && !(t & 1)) { int o = t >> 1; if (o < 21) { ozv[nz] = o; kzv[nz] = k; ++nz; } }
    }
#pragma unroll
    for (int k = 0; k < 3; ++k) {
        int t = y + 1 - k;
        if (t >= 0 && !(t & 1)) { int o = t >> 1; if (o < 256) { oyv[ny] = o; kyv[ny] = k; ++ny; } }
    }
#pragma unroll
    for (int k = 0; k < 3; ++k) {
        int t = x + 1 - k;
        if (t >= 0 && !(t & 1)) { int o = t >> 1; if (o < 256) { oxv[nx] = o; kxv[nx] = k; ++nx; } }
    }

    for (int a = 0; a < nz; ++a)
        for (int bb = 0; bb < ny; ++bb)
            for (int c = 0; c < nx; ++c) {
                const int oz = ozv[a], oy = oyv[bb], ox = oxv[c];
                const int tap = (kzv[a] * 3 + kyv[bb]) * 3 + kxv[c];
                const int sp = oz * 65536 + oy * 256 + ox;
                if (oc == 0) m1[b * 1376256 + sp] = 1.0f;
                const float s = ws[oc * 81 + tap] * f0 + ws[oc * 81 + 27 + tap] * f1 +
                                ws[oc * 81 + 54 + tap] * f2;
                atomicAdd(&y1[(b * 4 + oc4) * 5505024 + sp * 4 + ocl], s);
            }
}

// ---------------- Layer 2: dense conv 16->32, k3, s2, pad(1,1,1) ----------------
// 128-thr blocks, 16x8 px tile, all 32 oc per thread. 8 phases x 2 cin,
// 2 LDS planes (14.3 KB -> 11 blocks/CU = 22 waves): many small barrier
// groups give the cross-block staging/compute overlap (conv_l3 r5 recipe).
#define NE2 1683            // 3*17*33
#define PAD2 1792           // 14*128
__global__ __launch_bounds__(128) __attribute__((amdgpu_waves_per_eu(5, 8)))
void conv_l2(
    const float2* __restrict__ y12, const float* __restrict__ m1,
    const float* __restrict__ wT2, const float* __restrict__ shb,
    const float* __restrict__ g1, const float* __restrict__ bb1,
    const float* __restrict__ rm1, const float* __restrict__ rv1,
    float* __restrict__ h2, float* __restrict__ m2)
{
    __shared__ float sIn[2 * PAD2];      // mask staged in plane 0 first
    const int tid = threadIdx.x;
    const int tx = tid & 15, ty = tid >> 4;             // 16 x 8 spatial tile
    const int ox0 = blockIdx.x * 16, oy0 = blockIdx.y * 8;
    const int bz = blockIdx.z;
    const int b = bz / 11, oz = bz % 11;
    const int iz0 = 2 * oz - 1, iy0 = 2 * oy0 - 1, ix0 = 2 * ox0 - 1;

    // stage mask tile into plane 0
    for (int e = tid; e < NE2; e += 128) {
        const int ez = e / 561, r = e % 561, ey = r / 33, ex = r % 33;
        const int iz = iz0 + ez, iy = iy0 + ey, ix = ix0 + ex;
        float mv = 0.f;
        if ((unsigned)iz < 21u && (unsigned)iy < 256u && (unsigned)ix < 256u)
            mv = m1[b * 1376256 + iz * 65536 + iy * 256 + ix];
        sIn[e] = mv;
    }
    __syncthreads();

    float msum = 0.f;
#pragma unroll
    for (int kz = 0; kz < 3; ++kz)
#pragma unroll
        for (int ky = 0; ky < 3; ++ky)
#pragma unroll
            for (int kx = 0; kx < 3; ++kx)
                msum += sIn[kz * 561 + (2 * ty + ky) * 33 + 2 * tx + kx];
    const float mout = msum > 0.f ? 1.f : 0.f;

    // hoisted per-thread staging offsets (float2-element units) + mask values
    int   q14[14];
    float mk14[14];
#pragma unroll
    for (int j = 0; j < 14; ++j) {
        const int e = tid + j * 128;
        const int ez = e / 561, r = e % 561, ey = r / 33, ex = r % 33;
        const int iz = iz0 + ez, iy = iy0 + ey, ix = ix0 + ex;
        const bool ok = (e < NE2) && (unsigned)iz < 21u && (unsigned)iy < 256u &&
                        (unsigned)ix < 256u;
        const int sp = iz * 65536 + iy * 256 + ix;
        q14[j] = ok ? (b * 11010048 + sp * 2) : 0;   // float2 units
        mk14[j] = ok ? sIn[e] : 0.f;
    }
    __syncthreads();   // mask consumed into registers; plane 0 reusable

    float acc[32];
#pragma unroll
    for (int oc = 0; oc < 32; ++oc) acc[oc] = 0.f;

#pragma unroll 1
    for (int cp = 0; cp < 8; ++cp) {                 // channel pair
        const int oc4 = cp >> 1, p = cp & 1;
        const int base = oc4 * 2752512 + p;          // float2 units
        float inv[2], sh[2];
#pragma unroll
        for (int c = 0; c < 2; ++c) {
            const int cin = cp * 2 + c;
            inv[c] = g1[cin] * rsqrtf(rv1[cin] + EPS);
            sh[c] = bb1[cin] - rm1[cin] * inv[c];
        }
#pragma unroll
        for (int j = 0; j < 14; ++j) {
            const float2 v = y12[q14[j] + base];
            const int e = tid + j * 128;
            sIn[0 * PAD2 + e] = fmaxf(v.x * inv[0] + sh[0], 0.f) * mk14[j];
            sIn[1 * PAD2 + e] = fmaxf(v.y * inv[1] + sh[1], 0.f) * mk14[j];
        }
        __syncthreads();        // LDS published

#pragma unroll
        for (int c = 0; c < 2; ++c) {
            const float* __restrict__ wq = wT2 + (cp * 2 + c) * 864;   // block-uniform
#pragma unroll
            for (int kz = 0; kz < 3; ++kz)
#pragma unroll
                for (int ky = 0; ky < 3; ++ky)
#pragma unroll
                    for (int kx = 0; kx < 3; ++kx) {
                        const int tap = (kz * 3 + ky) * 3 + kx;
                        const float vt = sIn[c * PAD2 + kz * 561 + (2 * ty + ky) * 33 +
                                             2 * tx + kx];
#pragma unroll
                        for (int oc = 0; oc < 32; ++oc)
                            acc[oc] = fmaf(wq[tap * 32 + oc], vt, acc[oc]);
                    }
        }
        __syncthreads();        // LDS consumed
    }

    const int oy = oy0 + ty, ox = ox0 + tx;
    m2[((b * 11 + oz) * 128 + oy) * 128 + ox] = mout;
#pragma unroll
    for (int oc = 0; oc < 32; ++oc) {
        h2[(((b * 32 + oc) * 11 + oz) * 128 + oy) * 128 + ox] =
            fmaxf(acc[oc] + shb[oc], 0.f) * mout;
    }
}

// ---------------- Layer 3 (partial): conv 32->64, k3, s2, pad(0,1,1) ----------------
// 128-thr blocks, 16x8 px tile, 16 oc/thread (4 oc-groups), cin split in 2.
// Next cin's loads register-prefetched (14 scalars -- small, no spill).
#define NE3 1683            // 3*17*33
#define PAD3 1792           // 14*128
__global__ __launch_bounds__(128) __attribute__((amdgpu_waves_per_eu(4, 8)))
void conv_l3(
    const float* __restrict__ h2, const float* __restrict__ m2,
    const float* __restrict__ wT3,
    float* __restrict__ p3a, float* __restrict__ p3b, float* __restrict__ m3)
{
    __shared__ float sIn[PAD3];
    __shared__ float sM[PAD3];
    const int tid = threadIdx.x;
    const int tx = tid & 15, ty = tid >> 4;             // 16 x 8 spatial tile
    const int ocg = blockIdx.x >> 2;                    // 0..3 (16 oc each)
    const int ox0 = (blockIdx.x & 3) * 16, oy0 = blockIdx.y * 8;
    const int bz = blockIdx.z;
    const int half = bz / 10, rz = bz % 10;
    const int b = rz / 5, oz = rz % 5;
    const int iz0 = 2 * oz, iy0 = 2 * oy0 - 1, ix0 = 2 * ox0 - 1;  // z pad 0

    const bool needM = (half == 0) && (ocg == 0);
    if (needM) {
        for (int e = tid; e < NE3; e += 128) {
            const int ez = e / 561, rr = e % 561, ey = rr / 33, ex = rr % 33;
            const int iz = iz0 + ez, iy = iy0 + ey, ix = ix0 + ex;
            float mv = 0.f;
            if ((unsigned)iy < 128u && (unsigned)ix < 128u)  // iz always in [0,10]
                mv = m2[((b * 11 + iz) * 128 + iy) * 128 + ix];
            sM[e] = mv;
        }
        __syncthreads();
    }

    int   q14[14];
    float ok14[14];
#pragma unroll
    for (int j = 0; j < 14; ++j) {
        const int e = tid + j * 128;
        const int ez = e / 561, rr = e % 561, ey = rr / 33, ex = rr % 33;
        const int iz = iz0 + ez, iy = iy0 + ey, ix = ix0 + ex;
        const bool ok = (e < NE3) && (unsigned)iy < 128u && (unsigned)ix < 128u;
        q14[j] = ok ? (b * 5767168 + iz * 16384 + iy * 128 + ix) : 0;
        ok14[j] = ok ? 1.f : 0.f;
    }

    const int cin0 = half * 16;
    float pre[14];
#pragma unroll
    for (int j = 0; j < 14; ++j) pre[j] = h2[q14[j] + cin0 * 180224];

    float acc[16];
#pragma unroll
    for (int oc = 0; oc < 16; ++oc) acc[oc] = 0.f;

#pragma unroll 1
    for (int c = 0; c < 16; ++c) {
        const int cin = cin0 + c;
#pragma unroll
        for (int j = 0; j < 14; ++j)
            sIn[tid + j * 128] = pre[j] * ok14[j];
        __syncthreads();        // LDS published

        if (c < 15) {
#pragma unroll
            for (int j = 0; j < 14; ++j) pre[j] = h2[q14[j] + (cin + 1) * 180224];
        }

        const float* __restrict__ wq = wT3 + cin * 1728 + ocg * 16;  // block-uniform
#pragma unroll
        for (int kz = 0; kz < 3; ++kz)
#pragma unroll
            for (int ky = 0; ky < 3; ++ky)
#pragma unroll
                for (int kx = 0; kx < 3; ++kx) {
                    const int tap = (kz * 3 + ky) * 3 + kx;
                    const float vt = sIn[kz * 561 + (2 * ty + ky) * 33 + 2 * tx + kx];
#pragma unroll
                    for (int oc = 0; oc < 16; ++oc)
                        acc[oc] = fmaf(wq[tap * 64 + oc], vt, acc[oc]);
                }
        __syncthreads();        // LDS consumed
    }

    const int oy = oy0 + ty, ox = ox0 + tx;
    if (needM) {
        float msum = 0.f;
#pragma unroll
        for (int kz = 0; kz < 3; ++kz)
#pragma unroll
            for (int ky = 0; ky < 3; ++ky)
#pragma unroll
                for (int kx = 0; kx < 3; ++kx)
                    msum += sM[kz * 561 + (2 * ty + ky) * 33 + 2 * tx + kx];
        m3[(b * 5 + oz) * 4096 + oy * 64 + ox] = msum > 0.f ? 1.f : 0.f;
    }

    float* __restrict__ part = half ? p3b : p3a;
#pragma unroll
    for (int oc = 0; oc < 16; ++oc) {
        const int ocgl = ocg * 16 + oc;
        part[(((b * 64 + ocgl) * 5 + oz) * 64 + oy) * 64 + ox] = acc[oc];
    }
}

// ---------------- Layer 3 combine: h3 = relu(pa+pb+shift)*m3 ----------------
__global__ __launch_bounds__(256) void combine_l3(
    const float* __restrict__ p3a, const float* __restrict__ p3b,
    const float* __restrict__ m3, const float* __restrict__ shb,
    float* __restrict__ h3)
{
    const int idx = blockIdx.x * 256 + threadIdx.x;   // < 2,621,440
    const int b = idx / 1310720;
    const int r = idx - b * 1310720;
    const int oc = r / 20480;
    const int r2 = r - oc * 20480;
    const float mv = m3[b * 20480 + r2];
    h3[idx] = fmaxf(p3a[idx] + p3b[idx] + shb[32 + oc], 0.f) * mv;
}

// ---------------- Layer 4: conv 64->64, k(3,1,1), s(2,1,1), pad 0 ----------------
__global__ __launch_bounds__(256) __attribute__((amdgpu_waves_per_eu(4, 8)))
void conv_l4(
    const float* __restrict__ h3, const float* __restrict__ m3,
    const float* __restrict__ wT4, const float* __restrict__ shb,
    float* __restrict__ out)
{
    const int p = blockIdx.x * 256 + threadIdx.x;  // 0..4095 spatial
    const int bo = blockIdx.y;
    const int b = bo >> 4, od = (bo >> 3) & 1, ocg = bo & 7;

    const float msum = m3[(b * 5 + 2 * od + 0) * 4096 + p] +
                       m3[(b * 5 + 2 * od + 1) * 4096 + p] +
                       m3[(b * 5 + 2 * od + 2) * 4096 + p];
    const float mout = msum > 0.f ? 1.f : 0.f;

    float acc[8];
#pragma unroll
    for (int oc = 0; oc < 8; ++oc) acc[oc] = 0.f;

#pragma unroll 1
    for (int c = 0; c < 64; ++c) {
        const float v0 = h3[((b * 64 + c) * 5 + 2 * od + 0) * 4096 + p];
        const float v1 = h3[((b * 64 + c) * 5 + 2 * od + 1) * 4096 + p];
        const float v2 = h3[((b * 64 + c) * 5 + 2 * od + 2) * 4096 + p];
        const float* __restrict__ wq = wT4 + c * 192 + ocg * 8;  // block-uniform
#pragma unroll
        for (int oc = 0; oc < 8; ++oc) {
            acc[oc] = fmaf(wq[oc], v0,
                      fmaf(wq[64 + oc], v1,
                      fmaf(wq[128 + oc], v2, acc[oc])));
        }
    }

#pragma unroll
    for (int oc = 0; oc < 8; ++oc) {
        const int ocgl = ocg * 8 + oc;
        out[((b * 64 + ocgl) * 2 + od) * 4096 + p] =
            fmaxf(acc[oc] + shb[96 + ocgl], 0.f) * mout;
    }
}

extern "C" void kernel_launch(void* const* d_in, const int* in_sizes, int n_in,
                              void* d_out, int out_size, void* d_ws, size_t ws_size,
                              hipStream_t stream)
{
    const float* vf    = (const float*)d_in[0];
    const int*   coors = (const int*)d_in[1];
    // d_in[2] = batch_size (==2, hardcoded in geometry)
    const float* w1 = (const float*)d_in[3];
    const float* g1 = (const float*)d_in[4];
    const float* b1 = (const float*)d_in[5];
    const float* rm1 = (const float*)d_in[6];
    const float* rv1 = (const float*)d_in[7];
    const float* w2 = (const float*)d_in[8];
    const float* g2 = (const float*)d_in[9];
    const float* b2 = (const float*)d_in[10];
    const float* rm2 = (const float*)d_in[11];
    const float* rv2 = (const float*)d_in[12];
    const float* w3 = (const float*)d_in[13];
    const float* g3 = (const float*)d_in[14];
    const float* b3 = (const float*)d_in[15];
    const float* rm3 = (const float*)d_in[16];
    const float* rv3 = (const float*)d_in[17];
    const float* w4 = (const float*)d_in[18];
    const float* g4 = (const float*)d_in[19];
    const float* b4 = (const float*)d_in[20];
    const float* rm4 = (const float*)d_in[21];
    const float* rv4 = (const float*)d_in[22];

    const int NV = in_sizes[0] / 3;

    float* ws = (float*)d_ws;
    float* y1  = ws;                   // 44,040,192 f  (2,4,21,256,256,4) interleaved
    float* m1  = y1 + 44040192;        //  2,752,512 f  (2,21,256,256)
    float* h2  = m1 + 2752512;         // 11,534,336 f  (2,32,11,128,128)
    float* m2  = h2 + 11534336;        //    360,448 f  (2,11,128,128)
    float* h3  = m2 + 360448;          //  2,621,440 f  (2,64,5,64,64)
    float* m3  = h3 + 2621440;         //     40,960 f  (2,5,64,64)
    float* wT2 = m3 + 40960;           //     13,824 f
    float* wT3 = wT2 + 13824;          //     55,296 f
    float* wT4 = wT3 + 55296;          //     12,288 f
    float* shb = wT4 + 12288;          //        160 f
    // Partial buffers for conv_l3 overlay the y1 region (y1 dead after conv_l2).
    float* p3a = y1;                   //  2,621,440 f
    float* p3b = y1 + 2621440;         //  2,621,440 f

    // zero the scatter accumulator + mask (y1 and m1 are contiguous)
    hipMemsetAsync(y1, 0, (size_t)(44040192 + 2752512) * sizeof(float), stream);

    repack<<<319, 256, 0, stream>>>(w2, g2, b2, rm2, rv2, w3, g3, b3, rm3, rv3,
                                    w4, g4, b4, rm4, rv4, wT2, wT3, wT4, shb);
    scatter_l1<<<(NV * 16 + 255) / 256, 256, 0, stream>>>(vf, coors, NV, w1, y1, m1);
    conv_l2<<<dim3(8, 16, 22), 128, 0, stream>>>((const float2*)y1, m1, wT2, shb,
                                                 g1, b1, rm1, rv1, h2, m2);
    conv_l3<<<dim3(16, 8, 20), 128, 0, stream>>>(h2, m2, wT3, p3a, p3b, m3);
    combine_l3<<<10240, 256, 0, stream>>>(p3a, p3b, m3, shb, h3);
    conv_l4<<<dim3(16, 32), 256, 0, stream>>>(h3, m3, wT4, shb, (float*)d_out);
}

// Round 10
// 475.510 us; speedup vs baseline: 1.4403x; 1.4403x over previous
//
#include <hip/hip_runtime.h>

#define EPS 1e-3f

// Tensor geometry (fixed for this problem):
// y1 (L1 pre-act): interleaved (2, 4, 21,256,256, 4)  = (b, c/4, z,y,x, c%4)
// m1: (2,21,256,256)
// L2 out (h2): (2,32,11,128,128)  m2: (2,11,128,128)
// L3 out (h3): (2,64,5,64,64)     m3: (2,5,64,64)
// L4 out:      (2,64,2,64,64) -> d_out (2,128,64,64) same layout
//
// Lessons encoded:
//  - Weight pointers must be BLOCK-uniform (scalar s_load path). (r2: 3.6x regression)
//  - In-thread register prefetch >~20 regs spills to scratch. (r7)
//  - The phase-barrier LDS-staging structure pins conv_l2 at ~350-380 us across
//    ALL granularities (r6/r8/r9: 4-wave, half-LDS, 2-wave variants identical;
//    occupancy stuck ~35%, offset arrays spilled). Fix: direct conv -- no LDS,
//    no barriers, no index arrays; mask-predicated tap loop; L1/L2 for reuse.
//  - Scatter is memory-REQUEST bound -> channel-quad interleaved y1. (r5/r6)
//  - conv_l3: cin-split x2 into fp32 partials + combine for grid occupancy. (r4/r5)

// ---------------- Weight repack + BN fold ----------------
// wT2: [tap][cin][oc] (27x16x32); wT3: [(cin*27+tap)*64+oc]; wT4: [(c*3+kz)*64+oc]
// shb: [0..31]=sh2, [32..95]=sh3, [96..159]=sh4, [160..175]=sc1, [176..191]=sh1
__global__ __launch_bounds__(256) void repack(
    const float* __restrict__ g1, const float* __restrict__ b1,
    const float* __restrict__ rm1, const float* __restrict__ rv1,
    const float* __restrict__ w2, const float* __restrict__ g2, const float* __restrict__ b2,
    const float* __restrict__ rm2, const float* __restrict__ rv2,
    const float* __restrict__ w3, const float* __restrict__ g3, const float* __restrict__ b3,
    const float* __restrict__ rm3, const float* __restrict__ rv3,
    const float* __restrict__ w4, const float* __restrict__ g4, const float* __restrict__ b4,
    const float* __restrict__ rm4, const float* __restrict__ rv4,
    float* __restrict__ wT2, float* __restrict__ wT3, float* __restrict__ wT4,
    float* __restrict__ shb)
{
    const int i = blockIdx.x * 256 + threadIdx.x;
    if (i < 13824) {                       // wT2[tap*512 + cin*32 + oc]
        const int tap = i / 512, cin = (i / 32) % 16, oc = i & 31;
        const float inv = g2[oc] * rsqrtf(rv2[oc] + EPS);
        wT2[i] = w2[(oc * 16 + cin) * 27 + tap] * inv;
    } else if (i < 69120) {                // wT3[(cin*27+tap)*64+oc], 32x27x64
        const int j = i - 13824;
        const int cin = j / 1728, tap = (j / 64) % 27, oc = j & 63;
        const float inv = g3[oc] * rsqrtf(rv3[oc] + EPS);
        wT3[j] = w3[(oc * 32 + cin) * 27 + tap] * inv;
    } else if (i < 81408) {                // wT4[(c*3+kz)*64+oc], 64x3x64
        const int j = i - 69120;
        const int c = j / 192, kz = (j / 64) % 3, oc = j & 63;
        const float inv = g4[oc] * rsqrtf(rv4[oc] + EPS);
        wT4[j] = w4[(oc * 64 + c) * 3 + kz] * inv;
    } else if (i < 81600) {                // shifts + L1 BN scale/shift
        const int j = i - 81408;
        if (j < 32) {
            const float inv = g2[j] * rsqrtf(rv2[j] + EPS);
            shb[j] = b2[j] - rm2[j] * inv;
        } else if (j < 96) {
            const int o = j - 32;
            const float inv = g3[o] * rsqrtf(rv3[o] + EPS);
            shb[j] = b3[o] - rm3[o] * inv;
        } else if (j < 160) {
            const int o = j - 96;
            const float inv = g4[o] * rsqrtf(rv4[o] + EPS);
            shb[j] = b4[o] - rm4[o] * inv;
        } else if (j < 176) {
            const int o = j - 160;
            shb[j] = g1[o] * rsqrtf(rv1[o] + EPS);           // sc1
        } else if (j < 192) {
            const int o = j - 176;
            const float inv = g1[o] * rsqrtf(rv1[o] + EPS);
            shb[j] = b1[o] - rm1[o] * inv;                   // sh1
        }
    }
}

// ---------------- Layer 1: voxel scatter, one thread per (voxel, oc) ----------------
__global__ __launch_bounds__(256) void scatter_l1(
    const float* __restrict__ vf, const int* __restrict__ coors, int NV,
    const float* __restrict__ w1, float* __restrict__ y1, float* __restrict__ m1)
{
    __shared__ float ws[16 * 3 * 27];  // (oc, c, tap)
    for (int e = threadIdx.x; e < 16 * 3 * 27; e += 256) ws[e] = w1[e];
    __syncthreads();

    const int gid = blockIdx.x * 256 + threadIdx.x;
    const int i = gid >> 4;        // voxel
    const int oc = gid & 15;       // channel
    if (i >= NV) return;
    const int oc4 = oc >> 2, ocl = oc & 3;

    const int b = coors[4 * i + 0];
    const int z = coors[4 * i + 1];
    const int y = coors[4 * i + 2];
    const int x = coors[4 * i + 3];
    const float f0 = vf[3 * i + 0];
    const float f1 = vf[3 * i + 1];
    const float f2 = vf[3 * i + 2];

    int ozv[2], kzv[2], nz = 0;
    int oyv[2], kyv[2], ny = 0;
    int oxv[2], kxv[2], nx = 0;
#pragma unroll
    for (int k = 0; k < 3; ++k) {
        int t = z + 1 - k;
        if (t >= 0 && !(t & 1)) { int o = t >> 1; if (o < 21) { ozv[nz] = o; kzv[nz] = k; ++nz; } }
    }
#pragma unroll
    for (int k = 0; k < 3; ++k) {
        int t = y + 1 - k;
        if (t >= 0 && !(t & 1)) { int o = t >> 1; if (o < 256) { oyv[ny] = o; kyv[ny] = k; ++ny; } }
    }
#pragma unroll
    for (int k = 0; k < 3; ++k) {
        int t = x + 1 - k;
        if (t >= 0 && !(t & 1)) { int o = t >> 1; if (o < 256) { oxv[nx] = o; kxv[nx] = k; ++nx; } }
    }

    for (int a = 0; a < nz; ++a)
        for (int bb = 0; bb < ny; ++bb)
            for (int c = 0; c < nx; ++c) {
                const int oz = ozv[a], oy = oyv[bb], ox = oxv[c];
                const int tap = (kzv[a] * 3 + kyv[bb]) * 3 + kxv[c];
                const int sp = oz * 65536 + oy * 256 + ox;
                if (oc == 0) m1[b * 1376256 + sp] = 1.0f;
                const float s = ws[oc * 81 + tap] * f0 + ws[oc * 81 + 27 + tap] * f1 +
                                ws[oc * 81 + 54 + tap] * f2;
                atomicAdd(&y1[(b * 4 + oc4) * 5505024 + sp * 4 + ocl], s);
            }
}

// ---------------- Layer 2: DIRECT conv 16->32, k3, s2, pad(1,1,1) ----------------
// One thread per output px, all 32 oc. No LDS, no barriers, no index arrays.
// Per tap: read m1; if 0 (=~70% of taps, random voxels) skip loads+acts;
// else 4 float4 quad loads + BN/ReLU (SGPR scale/shift) + 512 FMA (SGPR weights).
__global__ __launch_bounds__(128) __attribute__((amdgpu_waves_per_eu(4, 8)))
void conv_l2(
    const float4* __restrict__ y1q, const float* __restrict__ m1,
    const float* __restrict__ wT2, const float* __restrict__ shb,
    float* __restrict__ h2, float* __restrict__ m2)
{
    const int tid = threadIdx.x;
    const int tx = tid & 15, ty = tid >> 4;            // 16 x 8 px tile
    const int ox = blockIdx.x * 16 + tx, oy = blockIdx.y * 8 + ty;
    const int bz = blockIdx.z;
    const int b = bz / 11, oz = bz % 11;
    const int iz0 = 2 * oz - 1, iyb = 2 * oy - 1, ixb = 2 * ox - 1;

    // L1 BN params as uniforms (repacked by repack kernel) -> SGPRs
    float sc1[16], sh1[16];
#pragma unroll
    for (int c = 0; c < 16; ++c) { sc1[c] = shb[160 + c]; sh1[c] = shb[176 + c]; }

    float acc[32];
#pragma unroll
    for (int oc = 0; oc < 32; ++oc) acc[oc] = 0.f;
    float msum = 0.f;

#pragma unroll 1
    for (int kz = 0; kz < 3; ++kz) {
        const int iz = iz0 + kz;
        if ((unsigned)iz >= 21u) continue;             // block-uniform
#pragma unroll 1
        for (int ky = 0; ky < 3; ++ky) {
            const int iy = iyb + ky;
#pragma unroll 1
            for (int kx = 0; kx < 3; ++kx) {
                const int ix = ixb + kx;
                const bool ok = (unsigned)iy < 256u && (unsigned)ix < 256u;
                const int sp = iz * 65536 + iy * 256 + ix;
                float mv = 0.f;
                if (ok) mv = m1[b * 1376256 + sp];
                msum += mv;
                if (mv > 0.f) {
                    const int tap = (kz * 3 + ky) * 3 + kx;
                    const float* __restrict__ wq = wT2 + tap * 512;   // block-uniform
#pragma unroll
                    for (int q = 0; q < 4; ++q) {
                        const float4 a = y1q[(b * 4 + q) * 1376256 + sp];
                        const int c0 = q * 4;
                        const float v0 = fmaxf(a.x * sc1[c0 + 0] + sh1[c0 + 0], 0.f);
                        const float v1 = fmaxf(a.y * sc1[c0 + 1] + sh1[c0 + 1], 0.f);
                        const float v2 = fmaxf(a.z * sc1[c0 + 2] + sh1[c0 + 2], 0.f);
                        const float v3 = fmaxf(a.w * sc1[c0 + 3] + sh1[c0 + 3], 0.f);
#pragma unroll
                        for (int oc = 0; oc < 32; ++oc) {
                            acc[oc] = fmaf(wq[(c0 + 0) * 32 + oc], v0,
                                      fmaf(wq[(c0 + 1) * 32 + oc], v1,
                                      fmaf(wq[(c0 + 2) * 32 + oc], v2,
                                      fmaf(wq[(c0 + 3) * 32 + oc], v3, acc[oc]))));
                        }
                    }
                }
            }
        }
    }

    const float mout = msum > 0.f ? 1.f : 0.f;
    m2[((b * 11 + oz) * 128 + oy) * 128 + ox] = mout;
#pragma unroll
    for (int oc = 0; oc < 32; ++oc) {
        h2[(((b * 32 + oc) * 11 + oz) * 128 + oy) * 128 + ox] =
            fmaxf(acc[oc] + shb[oc], 0.f) * mout;
    }
}

// ---------------- Layer 3 (partial): conv 32->64, k3, s2, pad(0,1,1) ----------------
// 128-thr blocks, 16x8 px tile, 16 oc/thread (4 oc-groups), cin split in 2.
#define NE3 1683            // 3*17*33
#define PAD3 1792           // 14*128
__global__ __launch_bounds__(128) __attribute__((amdgpu_waves_per_eu(4, 8)))
void conv_l3(
    const float* __restrict__ h2, const float* __restrict__ m2,
    const float* __restrict__ wT3,
    float* __restrict__ p3a, float* __restrict__ p3b, float* __restrict__ m3)
{
    __shared__ float sIn[PAD3];
    __shared__ float sM[PAD3];
    const int tid = threadIdx.x;
    const int tx = tid & 15, ty = tid >> 4;             // 16 x 8 spatial tile
    const int ocg = blockIdx.x >> 2;                    // 0..3 (16 oc each)
    const int ox0 = (blockIdx.x & 3) * 16, oy0 = blockIdx.y * 8;
    const int bz = blockIdx.z;
    const int half = bz / 10, rz = bz % 10;
    const int b = rz / 5, oz = rz % 5;
    const int iz0 = 2 * oz, iy0 = 2 * oy0 - 1, ix0 = 2 * ox0 - 1;  // z pad 0

    const bool needM = (half == 0) && (ocg == 0);
    if (needM) {
        for (int e = tid; e < NE3; e += 128) {
            const int ez = e / 561, rr = e % 561, ey = rr / 33, ex = rr % 33;
            const int iz = iz0 + ez, iy = iy0 + ey, ix = ix0 + ex;
            float mv = 0.f;
            if ((unsigned)iy < 128u && (unsigned)ix < 128u)  // iz always in [0,10]
                mv = m2[((b * 11 + iz) * 128 + iy) * 128 + ix];
            sM[e] = mv;
        }
        __syncthreads();
    }

    int   q14[14];
    float ok14[14];
#pragma unroll
    for (int j = 0; j < 14; ++j) {
        const int e = tid + j * 128;
        const int ez = e / 561, rr = e % 561, ey = rr / 33, ex = rr % 33;
        const int iz = iz0 + ez, iy = iy0 + ey, ix = ix0 + ex;
        const bool ok = (e < NE3) && (unsigned)iy < 128u && (unsigned)ix < 128u;
        q14[j] = ok ? (b * 5767168 + iz * 16384 + iy * 128 + ix) : 0;
        ok14[j] = ok ? 1.f : 0.f;
    }

    const int cin0 = half * 16;
    float pre[14];
#pragma unroll
    for (int j = 0; j < 14; ++j) pre[j] = h2[q14[j] + cin0 * 180224];

    float acc[16];
#pragma unroll
    for (int oc = 0; oc < 16; ++oc) acc[oc] = 0.f;

#pragma unroll 1
    for (int c = 0; c < 16; ++c) {
        const int cin = cin0 + c;
#pragma unroll
        for (int j = 0; j < 14; ++j)
            sIn[tid + j * 128] = pre[j] * ok14[j];
        __syncthreads();        // LDS published

        if (c < 15) {
#pragma unroll
            for (int j = 0; j < 14; ++j) pre[j] = h2[q14[j] + (cin + 1) * 180224];
        }

        const float* __restrict__ wq = wT3 + cin * 1728 + ocg * 16;  // block-uniform
#pragma unroll
        for (int kz = 0; kz < 3; ++kz)
#pragma unroll
            for (int ky = 0; ky < 3; ++ky)
#pragma unroll
                for (int kx = 0; kx < 3; ++kx) {
                    const int tap = (kz * 3 + ky) * 3 + kx;
                    const float vt = sIn[kz * 561 + (2 * ty + ky) * 33 + 2 * tx + kx];
#pragma unroll
                    for (int oc = 0; oc < 16; ++oc)
                        acc[oc] = fmaf(wq[tap * 64 + oc], vt, acc[oc]);
                }
        __syncthreads();        // LDS consumed
    }

    const int oy = oy0 + ty, ox = ox0 + tx;
    if (needM) {
        float msum = 0.f;
#pragma unroll
        for (int kz = 0; kz < 3; ++kz)
#pragma unroll
            for (int ky = 0; ky < 3; ++ky)
#pragma unroll
                for (int kx = 0; kx < 3; ++kx)
                    msum += sM[kz * 561 + (2 * ty + ky) * 33 + 2 * tx + kx];
        m3[(b * 5 + oz) * 4096 + oy * 64 + ox] = msum > 0.f ? 1.f : 0.f;
    }

    float* __restrict__ part = half ? p3b : p3a;
#pragma unroll
    for (int oc = 0; oc < 16; ++oc) {
        const int ocgl = ocg * 16 + oc;
        part[(((b * 64 + ocgl) * 5 + oz) * 64 + oy) * 64 + ox] = acc[oc];
    }
}

// ---------------- Layer 3 combine: h3 = relu(pa+pb+shift)*m3 ----------------
__global__ __launch_bounds__(256) void combine_l3(
    const float* __restrict__ p3a, const float* __restrict__ p3b,
    const float* __restrict__ m3, const float* __restrict__ shb,
    float* __restrict__ h3)
{
    const int idx = blockIdx.x * 256 + threadIdx.x;   // < 2,621,440
    const int b = idx / 1310720;
    const int r = idx - b * 1310720;
    const int oc = r / 20480;
    const int r2 = r - oc * 20480;
    const float mv = m3[b * 20480 + r2];
    h3[idx] = fmaxf(p3a[idx] + p3b[idx] + shb[32 + oc], 0.f) * mv;
}

// ---------------- Layer 4: conv 64->64, k(3,1,1), s(2,1,1), pad 0 ----------------
__global__ __launch_bounds__(256) __attribute__((amdgpu_waves_per_eu(4, 8)))
void conv_l4(
    const float* __restrict__ h3, const float* __restrict__ m3,
    const float* __restrict__ wT4, const float* __restrict__ shb,
    float* __restrict__ out)
{
    const int p = blockIdx.x * 256 + threadIdx.x;  // 0..4095 spatial
    const int bo = blockIdx.y;
    const int b = bo >> 4, od = (bo >> 3) & 1, ocg = bo & 7;

    const float msum = m3[(b * 5 + 2 * od + 0) * 4096 + p] +
                       m3[(b * 5 + 2 * od + 1) * 4096 + p] +
                       m3[(b * 5 + 2 * od + 2) * 4096 + p];
    const float mout = msum > 0.f ? 1.f : 0.f;

    float acc[8];
#pragma unroll
    for (int oc = 0; oc < 8; ++oc) acc[oc] = 0.f;

#pragma unroll 1
    for (int c = 0; c < 64; ++c) {
        const float v0 = h3[((b * 64 + c) * 5 + 2 * od + 0) * 4096 + p];
        const float v1 = h3[((b * 64 + c) * 5 + 2 * od + 1) * 4096 + p];
        const float v2 = h3[((b * 64 + c) * 5 + 2 * od + 2) * 4096 + p];
        const float* __restrict__ wq = wT4 + c * 192 + ocg * 8;  // block-uniform
#pragma unroll
        for (int oc = 0; oc < 8; ++oc) {
            acc[oc] = fmaf(wq[oc], v0,
                      fmaf(wq[64 + oc], v1,
                      fmaf(wq[128 + oc], v2, acc[oc])));
        }
    }

#pragma unroll
    for (int oc = 0; oc < 8; ++oc) {
        const int ocgl = ocg * 8 + oc;
        out[((b * 64 + ocgl) * 2 + od) * 4096 + p] =
            fmaxf(acc[oc] + shb[96 + ocgl], 0.f) * mout;
    }
}

extern "C" void kernel_launch(void* const* d_in, const int* in_sizes, int n_in,
                              void* d_out, int out_size, void* d_ws, size_t ws_size,
                              hipStream_t stream)
{
    const float* vf    = (const float*)d_in[0];
    const int*   coors = (const int*)d_in[1];
    // d_in[2] = batch_size (==2, hardcoded in geometry)
    const float* w1 = (const float*)d_in[3];
    const float* g1 = (const float*)d_in[4];
    const float* b1 = (const float*)d_in[5];
    const float* rm1 = (const float*)d_in[6];
    const float* rv1 = (const float*)d_in[7];
    const float* w2 = (const float*)d_in[8];
    const float* g2 = (const float*)d_in[9];
    const float* b2 = (const float*)d_in[10];
    const float* rm2 = (const float*)d_in[11];
    const float* rv2 = (const float*)d_in[12];
    const float* w3 = (const float*)d_in[13];
    const float* g3 = (const float*)d_in[14];
    const float* b3 = (const float*)d_in[15];
    const float* rm3 = (const float*)d_in[16];
    const float* rv3 = (const float*)d_in[17];
    const float* w4 = (const float*)d_in[18];
    const float* g4 = (const float*)d_in[19];
    const float* b4 = (const float*)d_in[20];
    const float* rm4 = (const float*)d_in[21];
    const float* rv4 = (const float*)d_in[22];

    const int NV = in_sizes[0] / 3;

    float* ws = (float*)d_ws;
    float* y1  = ws;                   // 44,040,192 f  (2,4,21,256,256,4) interleaved
    float* m1  = y1 + 44040192;        //  2,752,512 f  (2,21,256,256)
    float* h2  = m1 + 2752512;         // 11,534,336 f  (2,32,11,128,128)
    float* m2  = h2 + 11534336;        //    360,448 f  (2,11,128,128)
    float* h3  = m2 + 360448;          //  2,621,440 f  (2,64,5,64,64)
    float* m3  = h3 + 2621440;         //     40,960 f  (2,5,64,64)
    float* wT2 = m3 + 40960;           //     13,824 f
    float* wT3 = wT2 + 13824;          //     55,296 f
    float* wT4 = wT3 + 55296;          //     12,288 f
    float* shb = wT4 + 12288;          //        192 f
    // Partial buffers for conv_l3 overlay the y1 region (y1 dead after conv_l2).
    float* p3a = y1;                   //  2,621,440 f
    float* p3b = y1 + 2621440;         //  2,621,440 f

    // zero the scatter accumulator + mask (y1 and m1 are contiguous)
    hipMemsetAsync(y1, 0, (size_t)(44040192 + 2752512) * sizeof(float), stream);

    repack<<<319, 256, 0, stream>>>(g1, b1, rm1, rv1,
                                    w2, g2, b2, rm2, rv2, w3, g3, b3, rm3, rv3,
                                    w4, g4, b4, rm4, rv4, wT2, wT3, wT4, shb);
    scatter_l1<<<(NV * 16 + 255) / 256, 256, 0, stream>>>(vf, coors, NV, w1, y1, m1);
    conv_l2<<<dim3(8, 16, 22), 128, 0, stream>>>((const float4*)y1, m1, wT2, shb,
                                                 h2, m2);
    conv_l3<<<dim3(16, 8, 20), 128, 0, stream>>>(h2, m2, wT3, p3a, p3b, m3);
    combine_l3<<<10240, 256, 0, stream>>>(p3a, p3b, m3, shb, h3);
    conv_l4<<<dim3(16, 32), 256, 0, stream>>>(h3, m3, wT4, shb, (float*)d_out);
}

// Round 11
// 458.292 us; speedup vs baseline: 1.4944x; 1.0376x over previous
//
#include <hip/hip_runtime.h>

#define EPS 1e-3f

// Tensor geometry (fixed for this problem):
// y1 (L1 pre-act): quad-interleaved (2, 4, 21,256,256, 4) = (b, c/4, z,y,x, c%4)
// m1: (2,21,256,256)
// h2q: quad-interleaved (2, 8, 11,128,128, 4)   m2: (2,11,128,128)
// h3:  (2,64,5,64,64)  m3: (2,5,64,64)
// out: (2,64,2,64,64) -> d_out (2,128,64,64) same layout
//
// Lessons encoded:
//  - Weight pointers must be BLOCK-uniform (scalar path). (r2: 3.6x regression)
//  - In-thread register prefetch >~20 regs spills. (r7)
//  - Phase-barrier LDS staging pinned conv_l2 at ~350-380us across all
//    granularities (r6/r8/r9). DIRECT conv (no LDS/no barriers/no index arrays,
//    L1/L2 for reuse) took it to 181us (r10). Apply same to conv_l3.
//  - r10 conv_l2 was GRID-limited (5632 waves = 22/CU, occ 53%): oc-split x2
//    doubles waves; mask preload pipelines the 27 m1 loads.
//  - Scatter is memory-REQUEST bound -> channel-quad interleaved y1. (r5/r6)

// ---------------- Weight repack + BN fold ----------------
// wT2: [tap][cin][oc] 27x16x32; wT3: [tap][cin][oc] 27x32x64; wT4: [(c*3+kz)*64+oc]
// shb: [0..31]=sh2, [32..95]=sh3, [96..159]=sh4, [160..175]=sc1, [176..191]=sh1
__global__ __launch_bounds__(256) void repack(
    const float* __restrict__ g1, const float* __restrict__ b1,
    const float* __restrict__ rm1, const float* __restrict__ rv1,
    const float* __restrict__ w2, const float* __restrict__ g2, const float* __restrict__ b2,
    const float* __restrict__ rm2, const float* __restrict__ rv2,
    const float* __restrict__ w3, const float* __restrict__ g3, const float* __restrict__ b3,
    const float* __restrict__ rm3, const float* __restrict__ rv3,
    const float* __restrict__ w4, const float* __restrict__ g4, const float* __restrict__ b4,
    const float* __restrict__ rm4, const float* __restrict__ rv4,
    float* __restrict__ wT2, float* __restrict__ wT3, float* __restrict__ wT4,
    float* __restrict__ shb)
{
    const int i = blockIdx.x * 256 + threadIdx.x;
    if (i < 13824) {                       // wT2[tap*512 + cin*32 + oc]
        const int tap = i / 512, cin = (i / 32) % 16, oc = i & 31;
        const float inv = g2[oc] * rsqrtf(rv2[oc] + EPS);
        wT2[i] = w2[(oc * 16 + cin) * 27 + tap] * inv;
    } else if (i < 69120) {                // wT3[tap*2048 + cin*64 + oc]
        const int j = i - 13824;
        const int tap = j / 2048, cin = (j / 64) % 32, oc = j & 63;
        const float inv = g3[oc] * rsqrtf(rv3[oc] + EPS);
        wT3[j] = w3[(oc * 32 + cin) * 27 + tap] * inv;
    } else if (i < 81408) {                // wT4[(c*3+kz)*64+oc], 64x3x64
        const int j = i - 69120;
        const int c = j / 192, kz = (j / 64) % 3, oc = j & 63;
        const float inv = g4[oc] * rsqrtf(rv4[oc] + EPS);
        wT4[j] = w4[(oc * 64 + c) * 3 + kz] * inv;
    } else if (i < 81600) {                // shifts + L1 BN scale/shift
        const int j = i - 81408;
        if (j < 32) {
            const float inv = g2[j] * rsqrtf(rv2[j] + EPS);
            shb[j] = b2[j] - rm2[j] * inv;
        } else if (j < 96) {
            const int o = j - 32;
            const float inv = g3[o] * rsqrtf(rv3[o] + EPS);
            shb[j] = b3[o] - rm3[o] * inv;
        } else if (j < 160) {
            const int o = j - 96;
            const float inv = g4[o] * rsqrtf(rv4[o] + EPS);
            shb[j] = b4[o] - rm4[o] * inv;
        } else if (j < 176) {
            const int o = j - 160;
            shb[j] = g1[o] * rsqrtf(rv1[o] + EPS);           // sc1
        } else if (j < 192) {
            const int o = j - 176;
            const float inv = g1[o] * rsqrtf(rv1[o] + EPS);
            shb[j] = b1[o] - rm1[o] * inv;                   // sh1
        }
    }
}

// ---------------- Layer 1: voxel scatter, one thread per (voxel, oc) ----------------
__global__ __launch_bounds__(256) void scatter_l1(
    const float* __restrict__ vf, const int* __restrict__ coors, int NV,
    const float* __restrict__ w1, float* __restrict__ y1, float* __restrict__ m1)
{
    __shared__ float ws[16 * 3 * 27];  // (oc, c, tap)
    for (int e = threadIdx.x; e < 16 * 3 * 27; e += 256) ws[e] = w1[e];
    __syncthreads();

    const int gid = blockIdx.x * 256 + threadIdx.x;
    const int i = gid >> 4;        // voxel
    const int oc = gid & 15;       // channel
    if (i >= NV) return;
    const int oc4 = oc >> 2, ocl = oc & 3;

    const int b = coors[4 * i + 0];
    const int z = coors[4 * i + 1];
    const int y = coors[4 * i + 2];
    const int x = coors[4 * i + 3];
    const float f0 = vf[3 * i + 0];
    const float f1 = vf[3 * i + 1];
    const float f2 = vf[3 * i + 2];

    int ozv[2], kzv[2], nz = 0;
    int oyv[2], kyv[2], ny = 0;
    int oxv[2], kxv[2], nx = 0;
#pragma unroll
    for (int k = 0; k < 3; ++k) {
        int t = z + 1 - k;
        if (t >= 0 && !(t & 1)) { int o = t >> 1; if (o < 21) { ozv[nz] = o; kzv[nz] = k; ++nz; } }
    }
#pragma unroll
    for (int k = 0; k < 3; ++k) {
        int t = y + 1 - k;
        if (t >= 0 && !(t & 1)) { int o = t >> 1; if (o < 256) { oyv[ny] = o; kyv[ny] = k; ++ny; } }
    }
#pragma unroll
    for (int k = 0; k < 3; ++k) {
        int t = x + 1 - k;
        if (t >= 0 && !(t & 1)) { int o = t >> 1; if (o < 256) { oxv[nx] = o; kxv[nx] = k; ++nx; } }
    }

    for (int a = 0; a < nz; ++a)
        for (int bb = 0; bb < ny; ++bb)
            for (int c = 0; c < nx; ++c) {
                const int oz = ozv[a], oy = oyv[bb], ox = oxv[c];
                const int tap = (kzv[a] * 3 + kyv[bb]) * 3 + kxv[c];
                const int sp = oz * 65536 + oy * 256 + ox;
                if (oc == 0) m1[b * 1376256 + sp] = 1.0f;
                const float s = ws[oc * 81 + tap] * f0 + ws[oc * 81 + 27 + tap] * f1 +
                                ws[oc * 81 + 54 + tap] * f2;
                atomicAdd(&y1[(b * 4 + oc4) * 5505024 + sp * 4 + ocl], s);
            }
}

// ---------------- Layer 2: DIRECT conv 16->32, k3, s2, pad(1,1,1) ----------------
// One thread per (output px, 16-oc group). No LDS/barriers. 27 mask values
// preloaded (pipelined); active taps (~30%) do 4 quad loads + 256 FMA.
// Writes h2 as quad-interleaved h2q for conv_l3's vector loads.
__global__ __launch_bounds__(128) __attribute__((amdgpu_waves_per_eu(4, 8)))
void conv_l2(
    const float4* __restrict__ y1q, const float* __restrict__ m1,
    const float* __restrict__ wT2, const float* __restrict__ shb,
    float4* __restrict__ h2q, float* __restrict__ m2)
{
    const int tid = threadIdx.x;
    const int tx = tid & 15, ty = tid >> 4;            // 16 x 8 px tile
    const int ocg = blockIdx.x >> 3;                   // 0..1 (16 oc each)
    const int ox = (blockIdx.x & 7) * 16 + tx, oy = blockIdx.y * 8 + ty;
    const int bz = blockIdx.z;
    const int b = bz / 11, oz = bz % 11;
    const int iz0 = 2 * oz - 1, iyb = 2 * oy - 1, ixb = 2 * ox - 1;

    // L1 BN params as uniforms -> SGPRs
    float sc1[16], sh1[16];
#pragma unroll
    for (int c = 0; c < 16; ++c) { sc1[c] = shb[160 + c]; sh1[c] = shb[176 + c]; }

    // preload 27 mask values (independent loads pipeline)
    float mv[27];
    float msum = 0.f;
#pragma unroll
    for (int kz = 0; kz < 3; ++kz) {
        const int iz = iz0 + kz;
#pragma unroll
        for (int ky = 0; ky < 3; ++ky) {
            const int iy = iyb + ky;
#pragma unroll
            for (int kx = 0; kx < 3; ++kx) {
                const int ix = ixb + kx;
                float m = 0.f;
                if ((unsigned)iz < 21u && (unsigned)iy < 256u && (unsigned)ix < 256u)
                    m = m1[b * 1376256 + iz * 65536 + iy * 256 + ix];
                mv[(kz * 3 + ky) * 3 + kx] = m;
                msum += m;
            }
        }
    }

    float acc[16];
#pragma unroll
    for (int oc = 0; oc < 16; ++oc) acc[oc] = 0.f;

#pragma unroll 1
    for (int kz = 0; kz < 3; ++kz) {
        const int iz = iz0 + kz;
#pragma unroll 1
        for (int ky = 0; ky < 3; ++ky) {
            const int iy = iyb + ky;
#pragma unroll 1
            for (int kx = 0; kx < 3; ++kx) {
                const int tap = (kz * 3 + ky) * 3 + kx;
                if (mv[tap] > 0.f) {
                    const int ix = ixb + kx;
                    const int sp = iz * 65536 + iy * 256 + ix;
                    const float* __restrict__ wq = wT2 + tap * 512 + ocg * 16; // uniform
#pragma unroll
                    for (int q = 0; q < 4; ++q) {
                        const float4 a = y1q[(b * 4 + q) * 1376256 + sp];
                        const int c0 = q * 4;
                        const float v0 = fmaxf(a.x * sc1[c0 + 0] + sh1[c0 + 0], 0.f);
                        const float v1 = fmaxf(a.y * sc1[c0 + 1] + sh1[c0 + 1], 0.f);
                        const float v2 = fmaxf(a.z * sc1[c0 + 2] + sh1[c0 + 2], 0.f);
                        const float v3 = fmaxf(a.w * sc1[c0 + 3] + sh1[c0 + 3], 0.f);
#pragma unroll
                        for (int oc = 0; oc < 16; ++oc) {
                            acc[oc] = fmaf(wq[(c0 + 0) * 32 + oc], v0,
                                      fmaf(wq[(c0 + 1) * 32 + oc], v1,
                                      fmaf(wq[(c0 + 2) * 32 + oc], v2,
                                      fmaf(wq[(c0 + 3) * 32 + oc], v3, acc[oc]))));
                        }
                    }
                }
            }
        }
    }

    const float mout = msum > 0.f ? 1.f : 0.f;
    const int spo = oz * 16384 + oy * 128 + ox;
    if (ocg == 0) m2[b * 180224 + spo] = mout;
#pragma unroll
    for (int lq = 0; lq < 4; ++lq) {
        const int q = ocg * 4 + lq;
        float4 o;
        o.x = fmaxf(acc[lq * 4 + 0] + shb[ocg * 16 + lq * 4 + 0], 0.f) * mout;
        o.y = fmaxf(acc[lq * 4 + 1] + shb[ocg * 16 + lq * 4 + 1], 0.f) * mout;
        o.z = fmaxf(acc[lq * 4 + 2] + shb[ocg * 16 + lq * 4 + 2], 0.f) * mout;
        o.w = fmaxf(acc[lq * 4 + 3] + shb[ocg * 16 + lq * 4 + 3], 0.f) * mout;
        h2q[(b * 8 + q) * 180224 + spo] = o;
    }
}

// ---------------- Layer 3: DIRECT conv 32->64, k3, s2, pad(0,1,1) ----------------
// One thread per (output px, 8-oc group). Full 32-cin accumulation per thread;
// fused BN/ReLU/mask epilogue (combine kernel eliminated). h2 is dense-masked
// (already zeroed where m2=0), so no per-tap mask test -- only edge-OOB skip.
__global__ __launch_bounds__(128) __attribute__((amdgpu_waves_per_eu(4, 8)))
void conv_l3(
    const float4* __restrict__ h2q, const float* __restrict__ m2,
    const float* __restrict__ wT3, const float* __restrict__ shb,
    float* __restrict__ h3, float* __restrict__ m3)
{
    const int tid = threadIdx.x;
    const int tx = tid & 15, ty = tid >> 4;            // 16 x 8 px tile
    const int ocg = blockIdx.x >> 2;                   // 0..7 (8 oc each)
    const int ox = (blockIdx.x & 3) * 16 + tx, oy = blockIdx.y * 8 + ty;
    const int bz = blockIdx.z;
    const int b = bz / 5, oz = bz % 5;
    const int iz0 = 2 * oz, iyb = 2 * oy - 1, ixb = 2 * ox - 1;   // z pad 0

    float acc[8];
#pragma unroll
    for (int oc = 0; oc < 8; ++oc) acc[oc] = 0.f;
    float msum = 0.f;

#pragma unroll 1
    for (int kz = 0; kz < 3; ++kz) {
        const int iz = iz0 + kz;                       // always in [0,10]
#pragma unroll 1
        for (int ky = 0; ky < 3; ++ky) {
            const int iy = iyb + ky;
#pragma unroll 1
            for (int kx = 0; kx < 3; ++kx) {
                const int ix = ixb + kx;
                const bool ok = (unsigned)iy < 128u && (unsigned)ix < 128u;
                if (ok) {
                    const int sp = iz * 16384 + iy * 128 + ix;
                    msum += m2[b * 180224 + sp];
                    const int tap = (kz * 3 + ky) * 3 + kx;
                    const float* __restrict__ wq = wT3 + tap * 2048 + ocg * 8; // uniform
#pragma unroll
                    for (int q = 0; q < 8; ++q) {
                        const float4 a = h2q[(b * 8 + q) * 180224 + sp];
                        const int c0 = q * 4;
#pragma unroll
                        for (int oc = 0; oc < 8; ++oc) {
                            acc[oc] = fmaf(wq[(c0 + 0) * 64 + oc], a.x,
                                      fmaf(wq[(c0 + 1) * 64 + oc], a.y,
                                      fmaf(wq[(c0 + 2) * 64 + oc], a.z,
                                      fmaf(wq[(c0 + 3) * 64 + oc], a.w, acc[oc]))));
                        }
                    }
                }
            }
        }
    }

    const float mout = msum > 0.f ? 1.f : 0.f;
    const int spo = oz * 4096 + oy * 64 + ox;
    if (ocg == 0) m3[b * 20480 + spo] = mout;
#pragma unroll
    for (int oc = 0; oc < 8; ++oc) {
        const int ocg8 = ocg * 8 + oc;
        h3[(b * 64 + ocg8) * 20480 + spo] =
            fmaxf(acc[oc] + shb[32 + ocg8], 0.f) * mout;
    }
}

// ---------------- Layer 4: conv 64->64, k(3,1,1), s(2,1,1), pad 0 ----------------
__global__ __launch_bounds__(256) __attribute__((amdgpu_waves_per_eu(4, 8)))
void conv_l4(
    const float* __restrict__ h3, const float* __restrict__ m3,
    const float* __restrict__ wT4, const float* __restrict__ shb,
    float* __restrict__ out)
{
    const int p = blockIdx.x * 256 + threadIdx.x;  // 0..4095 spatial
    const int bo = blockIdx.y;
    const int b = bo >> 4, od = (bo >> 3) & 1, ocg = bo & 7;

    const float msum = m3[(b * 5 + 2 * od + 0) * 4096 + p] +
                       m3[(b * 5 + 2 * od + 1) * 4096 + p] +
                       m3[(b * 5 + 2 * od + 2) * 4096 + p];
    const float mout = msum > 0.f ? 1.f : 0.f;

    float acc[8];
#pragma unroll
    for (int oc = 0; oc < 8; ++oc) acc[oc] = 0.f;

#pragma unroll 1
    for (int c = 0; c < 64; ++c) {
        const float v0 = h3[((b * 64 + c) * 5 + 2 * od + 0) * 4096 + p];
        const float v1 = h3[((b * 64 + c) * 5 + 2 * od + 1) * 4096 + p];
        const float v2 = h3[((b * 64 + c) * 5 + 2 * od + 2) * 4096 + p];
        const float* __restrict__ wq = wT4 + c * 192 + ocg * 8;  // block-uniform
#pragma unroll
        for (int oc = 0; oc < 8; ++oc) {
            acc[oc] = fmaf(wq[oc], v0,
                      fmaf(wq[64 + oc], v1,
                      fmaf(wq[128 + oc], v2, acc[oc])));
        }
    }

#pragma unroll
    for (int oc = 0; oc < 8; ++oc) {
        const int ocgl = ocg * 8 + oc;
        out[((b * 64 + ocgl) * 2 + od) * 4096 + p] =
            fmaxf(acc[oc] + shb[96 + ocgl], 0.f) * mout;
    }
}

extern "C" void kernel_launch(void* const* d_in, const int* in_sizes, int n_in,
                              void* d_out, int out_size, void* d_ws, size_t ws_size,
                              hipStream_t stream)
{
    const float* vf    = (const float*)d_in[0];
    const int*   coors = (const int*)d_in[1];
    // d_in[2] = batch_size (==2, hardcoded in geometry)
    const float* w1 = (const float*)d_in[3];
    const float* g1 = (const float*)d_in[4];
    const float* b1 = (const float*)d_in[5];
    const float* rm1 = (const float*)d_in[6];
    const float* rv1 = (const float*)d_in[7];
    const float* w2 = (const float*)d_in[8];
    const float* g2 = (const float*)d_in[9];
    const float* b2 = (const float*)d_in[10];
    const float* rm2 = (const float*)d_in[11];
    const float* rv2 = (const float*)d_in[12];
    const float* w3 = (const float*)d_in[13];
    const float* g3 = (const float*)d_in[14];
    const float* b3 = (const float*)d_in[15];
    const float* rm3 = (const float*)d_in[16];
    const float* rv3 = (const float*)d_in[17];
    const float* w4 = (const float*)d_in[18];
    const float* g4 = (const float*)d_in[19];
    const float* b4 = (const float*)d_in[20];
    const float* rm4 = (const float*)d_in[21];
    const float* rv4 = (const float*)d_in[22];

    const int NV = in_sizes[0] / 3;

    float* ws = (float*)d_ws;
    float* y1  = ws;                   // 44,040,192 f  (2,4,21,256,256,4) interleaved
    float* m1  = y1 + 44040192;        //  2,752,512 f  (2,21,256,256)
    float* h2q = m1 + 2752512;         // 11,534,336 f  (2,8,11,128,128,4) interleaved
    float* m2  = h2q + 11534336;       //    360,448 f  (2,11,128,128)
    float* h3  = m2 + 360448;          //  2,621,440 f  (2,64,5,64,64)
    float* m3  = h3 + 2621440;         //     40,960 f  (2,5,64,64)
    float* wT2 = m3 + 40960;           //     13,824 f
    float* wT3 = wT2 + 13824;          //     55,296 f
    float* wT4 = wT3 + 55296;          //     12,288 f
    float* shb = wT4 + 12288;          //        192 f

    // zero the scatter accumulator + mask (y1 and m1 are contiguous)
    hipMemsetAsync(y1, 0, (size_t)(44040192 + 2752512) * sizeof(float), stream);

    repack<<<319, 256, 0, stream>>>(g1, b1, rm1, rv1,
                                    w2, g2, b2, rm2, rv2, w3, g3, b3, rm3, rv3,
                                    w4, g4, b4, rm4, rv4, wT2, wT3, wT4, shb);
    scatter_l1<<<(NV * 16 + 255) / 256, 256, 0, stream>>>(vf, coors, NV, w1, y1, m1);
    conv_l2<<<dim3(16, 16, 22), 128, 0, stream>>>((const float4*)y1, m1, wT2, shb,
                                                  (float4*)h2q, m2);
    conv_l3<<<dim3(32, 8, 10), 128, 0, stream>>>((const float4*)h2q, m2, wT3, shb,
                                                 h3, m3);
    conv_l4<<<dim3(16, 32), 256, 0, stream>>>(h3, m3, wT4, shb, (float*)d_out);
}